// Round 12
// baseline (1100.398 us; speedup 1.0000x reference)
//
#include <hip/hip_runtime.h>
#include <hip/hip_bf16.h>
#include <hip/hip_cooperative_groups.h>

namespace cg = cooperative_groups;

#define N_NODES 50000
#define N_PAD 50048  // Bm rows padded so MFMA frag loads stay in-bounds
#define N_EDGES 800000
#define DIM 96
#define CHB 12  // bf16 row = 96*2B = 12 x 16B chunks (8 features/thread)

#define EPB 2048                                   // edges per partition block
#define NB_E ((N_EDGES + EPB - 1) / EPB)           // 391
#define NBKT ((N_NODES + 255) / 256)               // 196 buckets of 256 nodes
#define NTILES ((N_NODES + 63) / 64)               // 782 gemm tiles

typedef __attribute__((ext_vector_type(8))) short short8;  // 8 bf16 = 4 VGPRs
typedef __attribute__((ext_vector_type(4))) float f32x4;

// ---------------- helpers ----------------

__device__ __forceinline__ unsigned short f2bf(float f) {  // RNE fp32->bf16 (finite)
    unsigned u = __float_as_uint(f);
    u += 0x7FFFu + ((u >> 16) & 1u);
    return (unsigned short)(u >> 16);
}

__device__ __forceinline__ int good_halves(unsigned w) {
    unsigned lo = w & 0xFFFFu, hi = w >> 16;
    unsigned e0 = (lo >> 7) & 0xFF, e1 = (hi >> 7) & 0xFF;
    int g = 0;
    if (lo == 0 || (e0 >= 100 && e0 <= 140)) ++g;
    if (hi == 0 || (e1 >= 100 && e1 <= 140)) ++g;
    return g;
}

__device__ __forceinline__ float rdval(const void* p, int i, int isbf) {
    return isbf ? __bfloat162float(((const __hip_bfloat16*)p)[i]) : ((const float*)p)[i];
}

__device__ __forceinline__ int load_idx(const int* __restrict__ p, int e, int is64) {
    return p[is64 ? (e << 1) : e];
}

// ---------------- pass 1: per-block bucket counts + flag publication ----------------
// detect folded in: every block derives is64 inline (L2-hot 512B probe);
// block 0 publishes flags[0..2] for later kernels.

__global__ __launch_bounds__(256) void part_count(const int* __restrict__ src,
                                                  const int* __restrict__ dst,
                                                  const unsigned* __restrict__ hw,
                                                  const unsigned* __restrict__ ww,
                                                  int* __restrict__ cntD,
                                                  int* __restrict__ cntS,
                                                  int* __restrict__ flags) {
    const unsigned* sw = (const unsigned*)src;
    int zeros = 0;
    for (int i = 0; i < 64; ++i) zeros += (sw[2 * i + 1] == 0u) ? 1 : 0;
    int is64 = (zeros >= 60) ? 1 : 0;

    __shared__ int lcD[256], lcS[256];
    int b = blockIdx.x, t = threadIdx.x;
    lcD[t] = 0; lcS[t] = 0;
    __syncthreads();
    int base = b * EPB;
#pragma unroll
    for (int i = 0; i < EPB / 256; ++i) {
        int e = base + i * 256 + t;
        if (e < N_EDGES) {
            int d = load_idx(dst, e, is64);
            int s = load_idx(src, e, is64);
            atomicAdd(&lcD[d >> 8], 1);
            atomicAdd(&lcS[s >> 8], 1);
        }
    }
    __syncthreads();
    cntD[b * 256 + t] = lcD[t];
    cntS[b * 256 + t] = lcS[t];

    if (b == 0) {
        if (t == 0) flags[2] = is64;
        if (t == 1) {
            int good = 0;
            for (int i = 0; i < 128; ++i) good += good_halves(hw[i]);
            flags[0] = (good >= 226) ? 1 : 0;
        }
        if (t == 2) {
            int good = 0;
            for (int i = 0; i < 128; ++i) good += good_halves(ww[i]);
            flags[1] = (good >= 226) ? 1 : 0;
        }
    }
}

// ---------------- pass 2: per-bucket exclusive scan over blocks (in-place) --------

__global__ __launch_bounds__(256) void scan_buckets(int* __restrict__ cntD,
                                                    int* __restrict__ cntS,
                                                    int* __restrict__ btotD,
                                                    int* __restrict__ btotS) {
    __shared__ int sm[256];
    int k = blockIdx.x, t = threadIdx.x;
    int b0 = 2 * t, b1 = 2 * t + 1;
    int v0 = (b0 < NB_E) ? cntD[b0 * 256 + k] : 0;
    int v1 = (b1 < NB_E) ? cntD[b1 * 256 + k] : 0;
    int pair = v0 + v1;
    sm[t] = pair;
    __syncthreads();
    for (int off = 1; off < 256; off <<= 1) {
        int u = (t >= off) ? sm[t - off] : 0;
        __syncthreads();
        sm[t] += u;
        __syncthreads();
    }
    int excl = sm[t] - pair;
    if (b0 < NB_E) cntD[b0 * 256 + k] = excl;
    if (b1 < NB_E) cntD[b1 * 256 + k] = excl + v0;
    if (t == 255) btotD[k] = sm[255];
    __syncthreads();
    v0 = (b0 < NB_E) ? cntS[b0 * 256 + k] : 0;
    v1 = (b1 < NB_E) ? cntS[b1 * 256 + k] : 0;
    pair = v0 + v1;
    sm[t] = pair;
    __syncthreads();
    for (int off = 1; off < 256; off <<= 1) {
        int u = (t >= off) ? sm[t - off] : 0;
        __syncthreads();
        sm[t] += u;
        __syncthreads();
    }
    excl = sm[t] - pair;
    if (b0 < NB_E) cntS[b0 * 256 + k] = excl;
    if (b1 < NB_E) cntS[b1 * 256 + k] = excl + v0;
    if (t == 255) btotS[k] = sm[255];
}

// ---------------- pass 3: scatter into buckets (bases re-scanned in LDS) ----------

__global__ __launch_bounds__(256) void part_scatter(const int* __restrict__ src,
                                                    const int* __restrict__ dst,
                                                    const int* __restrict__ offD,
                                                    const int* __restrict__ offS,
                                                    const int* __restrict__ btotD,
                                                    const int* __restrict__ btotS,
                                                    unsigned* __restrict__ epack,
                                                    unsigned char* __restrict__ sloc,
                                                    const int* __restrict__ flags) {
    __shared__ int sm[256];
    __shared__ int runD[256], runS[256];
    int b = blockIdx.x, t = threadIdx.x;
    int v = btotD[t];
    sm[t] = v;
    __syncthreads();
    for (int off = 1; off < 256; off <<= 1) {
        int u = (t >= off) ? sm[t - off] : 0;
        __syncthreads();
        sm[t] += u;
        __syncthreads();
    }
    int baseD = sm[t] - v;
    __syncthreads();
    v = btotS[t];
    sm[t] = v;
    __syncthreads();
    for (int off = 1; off < 256; off <<= 1) {
        int u = (t >= off) ? sm[t - off] : 0;
        __syncthreads();
        sm[t] += u;
        __syncthreads();
    }
    int baseS = sm[t] - v;
    runD[t] = baseD + offD[b * 256 + t];
    runS[t] = baseS + offS[b * 256 + t];
    __syncthreads();
    int is64 = flags[2];
    int base = b * EPB;
#pragma unroll
    for (int i = 0; i < EPB / 256; ++i) {
        int e = base + i * 256 + t;
        if (e < N_EDGES) {
            int d = load_idx(dst, e, is64);
            int s = load_idx(src, e, is64);
            int pd = atomicAdd(&runD[d >> 8], 1);
            epack[pd] = ((unsigned)(d & 255) << 16) | (unsigned)s;
            int ps = atomicAdd(&runS[s >> 8], 1);
            sloc[ps] = (unsigned char)(s & 255);
        }
    }
}

// ---------------- pass 4: per-bucket CSR build + norms + esrc (bases in LDS) -------

__global__ __launch_bounds__(256) void bucket_build(const unsigned* __restrict__ epack,
                                                    const int* __restrict__ btotD,
                                                    const unsigned char* __restrict__ sloc,
                                                    const int* __restrict__ btotS,
                                                    int* __restrict__ rowptr,
                                                    float* __restrict__ normD,
                                                    float* __restrict__ normS,
                                                    unsigned short* __restrict__ esrc) {
    __shared__ int bD[256], bS[256], cnt[256], run[256];
    int k = blockIdx.x, t = threadIdx.x;
    int vD = btotD[t], vS = btotS[t];
    bD[t] = vD; bS[t] = vS;
    __syncthreads();
    for (int off = 1; off < 256; off <<= 1) {
        int uD = (t >= off) ? bD[t - off] : 0;
        int uS = (t >= off) ? bS[t - off] : 0;
        __syncthreads();
        bD[t] += uD; bS[t] += uS;
        __syncthreads();
    }
    int ebeg = (k == 0) ? 0 : bD[k - 1];
    int eend = bD[k];
    int sbeg = (k == 0) ? 0 : bS[k - 1];
    int send = bS[k];

    cnt[t] = 0;
    __syncthreads();
    for (int e = ebeg + t; e < eend; e += 256)
        atomicAdd(&cnt[epack[e] >> 16], 1);
    __syncthreads();
    int v = cnt[t];
    bD[t] = v;  // reuse bD as scan buffer
    __syncthreads();
    for (int off = 1; off < 256; off <<= 1) {
        int u = (t >= off) ? bD[t - off] : 0;
        __syncthreads();
        bD[t] += u;
        __syncthreads();
    }
    int excl = bD[t] - v;
    int n = k * 256 + t;
    if (n < N_NODES) {
        rowptr[n] = ebeg + excl;
        normD[n] = rsqrtf((float)max(v, 1));
    }
    run[t] = excl;
    __syncthreads();
    for (int e = ebeg + t; e < eend; e += 256) {
        unsigned p = epack[e];
        int dl = p >> 16;
        int slot = atomicAdd(&run[dl], 1);
        esrc[ebeg + slot] = (unsigned short)(p & 0xFFFFu);
    }
    if (k == NBKT - 1 && t == 0) rowptr[N_NODES] = N_EDGES;
    // src histogram -> normS
    __syncthreads();
    cnt[t] = 0;
    __syncthreads();
    for (int e = sbeg + t; e < send; e += 256)
        atomicAdd(&cnt[sloc[e]], 1);
    __syncthreads();
    if (n < N_NODES) normS[n] = rsqrtf((float)max(cnt[t], 1));
}

// ---------------- shared bodies for the layer pipeline ----------------

__device__ __forceinline__ void prep_item(int idx, const void* W0, const void* W1,
                                          const void* W2, const void* b0, const void* b1,
                                          const void* b2, unsigned short* WT, float* biasc,
                                          int wbf) {
    if (idx < 3 * DIM * DIM) {
        int l = idx / (DIM * DIM);
        int i = idx - l * DIM * DIM;
        int k = i / DIM, n = i - k * DIM;
        const void* Wp = (l == 0) ? W0 : (l == 1) ? W1 : W2;
        WT[l * DIM * DIM + n * DIM + k] = f2bf(rdval(Wp, i, wbf));
    } else if (idx < 3 * DIM * DIM + 3 * DIM) {
        int j = idx - 3 * DIM * DIM;
        int l = j / DIM, c = j - l * DIM;
        const void* bp = (l == 0) ? b0 : (l == 1) ? b1 : b2;
        biasc[j] = rdval(bp, c, wbf);
    }
}

__device__ __forceinline__ void cvt_item(int i4, const void* h, const float* normS,
                                         unsigned short* out, int hbf) {
    int i = i4 * 4;
    float ns = normS[i / DIM];
    float v0, v1, v2, v3;
    if (hbf) {
        const __hip_bfloat16* hp = (const __hip_bfloat16*)h + i;
        v0 = __bfloat162float(hp[0]); v1 = __bfloat162float(hp[1]);
        v2 = __bfloat162float(hp[2]); v3 = __bfloat162float(hp[3]);
    } else {
        float4 v = ((const float4*)h)[i4];
        v0 = v.x; v1 = v.y; v2 = v.z; v3 = v.w;
    }
    ushort4 o;
    o.x = f2bf(v0 * ns); o.y = f2bf(v1 * ns);
    o.z = f2bf(v2 * ns); o.w = f2bf(v3 * ns);
    ((ushort4*)out)[i4] = o;
}

__device__ __forceinline__ void gather_item(int g, const unsigned* __restrict__ Abf,
                                            const float* __restrict__ normD,
                                            const int* __restrict__ rowptr,
                                            const unsigned short* __restrict__ esrc,
                                            unsigned short* __restrict__ Bm) {
    int n = g / CHB;
    int c = g - n * CHB;
    int beg = rowptr[n], end = rowptr[n + 1];
    float a0 = 0.f, a1 = 0.f, a2 = 0.f, a3 = 0.f;
    float a4 = 0.f, a5 = 0.f, a6 = 0.f, a7 = 0.f;
    const uint4* Ap = (const uint4*)Abf;
    int k = beg;
    for (; k + 2 <= end; k += 2) {
        int s0 = esrc[k], s1 = esrc[k + 1];
        uint4 q = Ap[s0 * CHB + c];
        uint4 r = Ap[s1 * CHB + c];
        a0 += __uint_as_float(q.x << 16);
        a1 += __uint_as_float(q.x & 0xFFFF0000u);
        a2 += __uint_as_float(q.y << 16);
        a3 += __uint_as_float(q.y & 0xFFFF0000u);
        a4 += __uint_as_float(q.z << 16);
        a5 += __uint_as_float(q.z & 0xFFFF0000u);
        a6 += __uint_as_float(q.w << 16);
        a7 += __uint_as_float(q.w & 0xFFFF0000u);
        a0 += __uint_as_float(r.x << 16);
        a1 += __uint_as_float(r.x & 0xFFFF0000u);
        a2 += __uint_as_float(r.y << 16);
        a3 += __uint_as_float(r.y & 0xFFFF0000u);
        a4 += __uint_as_float(r.z << 16);
        a5 += __uint_as_float(r.z & 0xFFFF0000u);
        a6 += __uint_as_float(r.w << 16);
        a7 += __uint_as_float(r.w & 0xFFFF0000u);
    }
    if (k < end) {
        int s0 = esrc[k];
        uint4 q = Ap[s0 * CHB + c];
        a0 += __uint_as_float(q.x << 16);
        a1 += __uint_as_float(q.x & 0xFFFF0000u);
        a2 += __uint_as_float(q.y << 16);
        a3 += __uint_as_float(q.y & 0xFFFF0000u);
        a4 += __uint_as_float(q.z << 16);
        a5 += __uint_as_float(q.z & 0xFFFF0000u);
        a6 += __uint_as_float(q.w << 16);
        a7 += __uint_as_float(q.w & 0xFFFF0000u);
    }
    float nd = normD[n];
    uint4 o;
    o.x = (unsigned)f2bf(a0 * nd) | ((unsigned)f2bf(a1 * nd) << 16);
    o.y = (unsigned)f2bf(a2 * nd) | ((unsigned)f2bf(a3 * nd) << 16);
    o.z = (unsigned)f2bf(a4 * nd) | ((unsigned)f2bf(a5 * nd) << 16);
    o.w = (unsigned)f2bf(a6 * nd) | ((unsigned)f2bf(a7 * nd) << 16);
    ((uint4*)Bm)[g] = o;
}

// MFMA tile: A[m=lane&15][k=quad*8+j] from Bm; B from W^T; C/D col=lane&15,row=quad*4+reg
__device__ __forceinline__ void gemm_tile(int tile, int wv, int lane,
                                          const unsigned short* __restrict__ Bm,
                                          const unsigned short* __restrict__ WTl,
                                          const float* __restrict__ bl,
                                          const float* __restrict__ normS,
                                          bool last, int obf,
                                          unsigned short* __restrict__ outA,
                                          void* __restrict__ outLast) {
    int quad = lane >> 4;
    int ln = lane & 15;
    int rowbase = tile * 64 + wv * 16;
    const short8* Ap = (const short8*)(Bm + (size_t)(rowbase + ln) * DIM + quad * 8);
    short8 a0 = Ap[0], a1 = Ap[4], a2 = Ap[8];
    float ns[4];
    if (!last) {
#pragma unroll
        for (int r = 0; r < 4; ++r)
            ns[r] = normS[min(rowbase + quad * 4 + r, N_NODES - 1)];
    }
#pragma unroll
    for (int ct = 0; ct < 6; ++ct) {
        const short8* Wp = (const short8*)(WTl + (size_t)(ct * 16 + ln) * DIM + quad * 8);
        short8 b0 = Wp[0], b1 = Wp[4], b2 = Wp[8];
        f32x4 acc = {0.f, 0.f, 0.f, 0.f};
        acc = __builtin_amdgcn_mfma_f32_16x16x32_bf16(a0, b0, acc, 0, 0, 0);
        acc = __builtin_amdgcn_mfma_f32_16x16x32_bf16(a1, b1, acc, 0, 0, 0);
        acc = __builtin_amdgcn_mfma_f32_16x16x32_bf16(a2, b2, acc, 0, 0, 0);
        int col = ct * 16 + ln;
        float bv = bl[col];
#pragma unroll
        for (int r = 0; r < 4; ++r) {
            int row = rowbase + quad * 4 + r;
            if (row < N_NODES) {
                float v = fmaxf(acc[r] + bv, 0.f);
                size_t idx = (size_t)row * DIM + col;
                if (last) {
                    if (obf)
                        ((__hip_bfloat16*)outLast)[idx] = __float2bfloat16(v);
                    else
                        ((float*)outLast)[idx] = v;
                } else {
                    outA[idx] = f2bf(v * ns[r]);
                }
            }
        }
    }
}

// ---------------- cooperative layer pipeline: prep+cvt, 3x(gather, gemm) ----------
// R11 post-mortem: ~90us of the 249us total was inter-dispatch overhead across 15
// launches. This kernel replaces 8 of them with 6 grid.sync()s.
// __launch_bounds__(256,8): cap 64 VGPR -> 8 blocks/CU co-resident, gather keeps
// full TLP (avoids R6's fusion-occupancy trap; phases run sequentially full-width).

struct LA {
    const void* h;
    const int* flags;
    const float* normS;
    const float* normD;
    const int* rowptr;
    const unsigned short* esrc;
    const void* W0; const void* W1; const void* W2;
    const void* b0; const void* b1; const void* b2;
    unsigned short* WT;
    float* biasc;
    unsigned short* A0;
    unsigned short* A1;
    unsigned short* Bm;
    void* dout;
};

__global__ __launch_bounds__(256, 8) void layers_kernel(LA a) {
    cg::grid_group grid = cg::this_grid();
    const int t = threadIdx.x;
    const int nthr = gridDim.x * 256;
    const int g0 = blockIdx.x * 256 + t;
    const int hbf = a.flags[0];
    const int wbf = a.flags[1];

    for (int idx = g0; idx < 3 * DIM * DIM + 3 * DIM; idx += nthr)
        prep_item(idx, a.W0, a.W1, a.W2, a.b0, a.b1, a.b2, a.WT, a.biasc, wbf);
    for (int i4 = g0; i4 < N_NODES * DIM / 4; i4 += nthr)
        cvt_item(i4, a.h, a.normS, a.A0, hbf);
    grid.sync();

    const unsigned short* Ain = a.A0;
    unsigned short* Aout = a.A1;
    const int wv = t >> 6;
    const int lane = t & 63;
    for (int l = 0; l < 3; ++l) {
        const unsigned* Abf = (const unsigned*)Ain;
        for (int g = g0; g < N_NODES * CHB; g += nthr)
            gather_item(g, Abf, a.normD, a.rowptr, a.esrc, a.Bm);
        grid.sync();
        const unsigned short* WTl = a.WT + l * DIM * DIM;
        const float* bl = a.biasc + l * DIM;
        bool last = (l == 2);
        for (int tile = blockIdx.x; tile < NTILES; tile += gridDim.x)
            gemm_tile(tile, wv, lane, a.Bm, WTl, bl, a.normS, last, hbf, Aout, a.dout);
        if (l < 2) grid.sync();
        const unsigned short* tmp = Ain;
        Ain = Aout;
        Aout = (unsigned short*)tmp;
    }
}

// ---------------- fallback standalone kernels (if cooperative launch fails) --------

__global__ __launch_bounds__(256) void prep_w_k(const void* W0, const void* W1, const void* W2,
                                                const void* b0, const void* b1, const void* b2,
                                                unsigned short* WT, float* biasc,
                                                const int* flags) {
    int idx = blockIdx.x * 256 + threadIdx.x;
    prep_item(idx, W0, W1, W2, b0, b1, b2, WT, biasc, flags[1]);
}

__global__ __launch_bounds__(256) void cvt_k(const void* h, const float* normS,
                                             unsigned short* out, const int* flags) {
    int i4 = blockIdx.x * 256 + threadIdx.x;
    if (i4 < N_NODES * DIM / 4) cvt_item(i4, h, normS, out, flags[0]);
}

__global__ __launch_bounds__(256) void gather_k(const unsigned* Abf, const float* normD,
                                                const int* rowptr, const unsigned short* esrc,
                                                unsigned short* Bm) {
    int g = blockIdx.x * 256 + threadIdx.x;
    if (g < N_NODES * CHB) gather_item(g, Abf, normD, rowptr, esrc, Bm);
}

__global__ __launch_bounds__(256) void gemm_k(const unsigned short* Bm, const float* normS,
                                              const unsigned short* WTl, const float* bl,
                                              unsigned short* outA, void* outLast,
                                              const int* flags, int last) {
    gemm_tile(blockIdx.x, threadIdx.x >> 6, threadIdx.x & 63, Bm, WTl, bl, normS,
              last != 0, flags[0], outA, outLast);
}

// ---------------- host launch ----------------

extern "C" void kernel_launch(void* const* d_in, const int* in_sizes, int n_in,
                              void* d_out, int out_size, void* d_ws, size_t ws_size,
                              hipStream_t stream) {
    const void* h = d_in[0];
    const int* src = (const int*)d_in[1];
    const int* dst = (const int*)d_in[2];

    // workspace layout (4B units; all sections 16B-aligned)
    int* flags = (int*)d_ws;                            // 4
    int* cntD = flags + 4;                              // 100096
    int* cntS = cntD + NB_E * 256;                      // 100096
    int* btotD = cntS + NB_E * 256;                     // 256
    int* btotS = btotD + 256;                           // 256
    int* rowptr = btotS + 256;                          // 50004
    float* normS = (float*)(rowptr + 50004);            // 50000
    float* normD = normS + N_NODES;                     // 50000
    unsigned short* WT = (unsigned short*)(normD + N_NODES);  // 3*9216 us
    float* biasc = (float*)(WT + 3 * DIM * DIM);        // 288
    unsigned* epack = (unsigned*)(biasc + 3 * DIM);     // 800000
    unsigned char* sloc = (unsigned char*)(epack + N_EDGES);   // 800000 B
    unsigned short* esrc = (unsigned short*)(sloc + N_EDGES);  // 800000 us
    unsigned short* Bm = esrc + N_EDGES;                // N_PAD*96 us
    unsigned short* A0 = Bm + (size_t)N_PAD * DIM;      // 4.8M us
    unsigned short* A1 = A0 + (size_t)N_NODES * DIM;    // 4.8M us

    part_count<<<NB_E, 256, 0, stream>>>(src, dst, (const unsigned*)h,
                                         (const unsigned*)d_in[3], cntD, cntS, flags);
    scan_buckets<<<256, 256, 0, stream>>>(cntD, cntS, btotD, btotS);
    part_scatter<<<NB_E, 256, 0, stream>>>(src, dst, cntD, cntS, btotD, btotS,
                                           epack, sloc, flags);
    bucket_build<<<NBKT, 256, 0, stream>>>(epack, btotD, sloc, btotS,
                                           rowptr, normD, normS, esrc);

    // cooperative layer pipeline
    LA la;
    la.h = h; la.flags = flags; la.normS = normS; la.normD = normD;
    la.rowptr = rowptr; la.esrc = esrc;
    la.W0 = d_in[3]; la.W1 = d_in[5]; la.W2 = d_in[7];
    la.b0 = d_in[4]; la.b1 = d_in[6]; la.b2 = d_in[8];
    la.WT = WT; la.biasc = biasc; la.A0 = A0; la.A1 = A1; la.Bm = Bm;
    la.dout = d_out;

    int maxb = 0;
    hipError_t qerr = hipOccupancyMaxActiveBlocksPerMultiprocessor(&maxb, layers_kernel, 256, 0);
    int numCU = 256;
    hipDeviceGetAttribute(&numCU, hipDeviceAttributeMultiprocessorCount, 0);
    int grid = (qerr == hipSuccess && maxb > 0) ? numCU * maxb : 0;
    if (grid > 2048) grid = 2048;

    hipError_t lerr = hipErrorUnknown;
    if (grid > 0) {
        void* kargs[] = {&la};
        lerr = hipLaunchCooperativeKernel(reinterpret_cast<const void*>(&layers_kernel),
                                          dim3(grid), dim3(256), kargs, 0, stream);
    }
    if (lerr != hipSuccess) {
        // fallback: split launches (R11 structure)
        prep_w_k<<<(3 * DIM * DIM + 3 * DIM + 255) / 256, 256, 0, stream>>>(
            la.W0, la.W1, la.W2, la.b0, la.b1, la.b2, WT, biasc, flags);
        cvt_k<<<(N_NODES * DIM / 4 + 255) / 256, 256, 0, stream>>>(h, normS, A0, flags);
        const int ggrid = (N_NODES * CHB + 255) / 256;
        gather_k<<<ggrid, 256, 0, stream>>>((const unsigned*)A0, normD, rowptr, esrc, Bm);
        gemm_k<<<NTILES, 256, 0, stream>>>(Bm, normS, WT, biasc, A1, nullptr, flags, 0);
        gather_k<<<ggrid, 256, 0, stream>>>((const unsigned*)A1, normD, rowptr, esrc, Bm);
        gemm_k<<<NTILES, 256, 0, stream>>>(Bm, normS, WT + DIM * DIM, biasc + DIM,
                                           A0, nullptr, flags, 0);
        gather_k<<<ggrid, 256, 0, stream>>>((const unsigned*)A0, normD, rowptr, esrc, Bm);
        gemm_k<<<NTILES, 256, 0, stream>>>(Bm, normS, WT + 2 * DIM * DIM, biasc + 2 * DIM,
                                           nullptr, d_out, flags, 1);
    }
}

// Round 13
// 262.359 us; speedup vs baseline: 4.1942x; 4.1942x over previous
//
#include <hip/hip_runtime.h>
#include <hip/hip_bf16.h>

#define N_NODES 50000
#define N_PAD 50048  // Bm rows padded so MFMA frag loads stay in-bounds
#define N_EDGES 800000
#define DIM 96
#define CHB 12  // bf16 row = 96*2B = 12 x 16B chunks (8 features/thread)

#define EPB 2048                                   // edges per partition block
#define NB_E ((N_EDGES + EPB - 1) / EPB)           // 391
#define NBKT ((N_NODES + 255) / 256)               // 196 buckets of 256 nodes
#define NTILES ((N_NODES + 63) / 64)               // 782 gemm tiles
#define PREP_ITEMS (3 * DIM * DIM + 3 * DIM)       // 27936

typedef __attribute__((ext_vector_type(8))) short short8;  // 8 bf16 = 4 VGPRs
typedef __attribute__((ext_vector_type(4))) float f32x4;

// R12 lesson (recorded): cooperative grid.sync() on MI355X costs ~250us/sync
// (8 non-coherent XCD L2s flush + 2048-block barrier spin; FETCH 160->348MB).
// Kernel boundaries are the cheap grid barrier on multi-XCD CDNA. Split launches.

// ---------------- helpers ----------------

__device__ __forceinline__ unsigned short f2bf(float f) {  // RNE fp32->bf16 (finite)
    unsigned u = __float_as_uint(f);
    u += 0x7FFFu + ((u >> 16) & 1u);
    return (unsigned short)(u >> 16);
}

__device__ __forceinline__ int good_halves(unsigned w) {
    unsigned lo = w & 0xFFFFu, hi = w >> 16;
    unsigned e0 = (lo >> 7) & 0xFF, e1 = (hi >> 7) & 0xFF;
    int g = 0;
    if (lo == 0 || (e0 >= 100 && e0 <= 140)) ++g;
    if (hi == 0 || (e1 >= 100 && e1 <= 140)) ++g;
    return g;
}

__device__ __forceinline__ float rdval(const void* p, int i, int isbf) {
    return isbf ? __bfloat162float(((const __hip_bfloat16*)p)[i]) : ((const float*)p)[i];
}

__device__ __forceinline__ int load_idx(const int* __restrict__ p, int e, int is64) {
    return p[is64 ? (e << 1) : e];
}

// ---------------- pass 1: per-block bucket counts + flag publication ----------------

__global__ __launch_bounds__(256) void part_count(const int* __restrict__ src,
                                                  const int* __restrict__ dst,
                                                  const unsigned* __restrict__ hw,
                                                  const unsigned* __restrict__ ww,
                                                  int* __restrict__ cntD,
                                                  int* __restrict__ cntS,
                                                  int* __restrict__ flags) {
    const unsigned* sw = (const unsigned*)src;
    int zeros = 0;
    for (int i = 0; i < 64; ++i) zeros += (sw[2 * i + 1] == 0u) ? 1 : 0;
    int is64 = (zeros >= 60) ? 1 : 0;

    __shared__ int lcD[256], lcS[256];
    int b = blockIdx.x, t = threadIdx.x;
    lcD[t] = 0; lcS[t] = 0;
    __syncthreads();
    int base = b * EPB;
#pragma unroll
    for (int i = 0; i < EPB / 256; ++i) {
        int e = base + i * 256 + t;
        if (e < N_EDGES) {
            int d = load_idx(dst, e, is64);
            int s = load_idx(src, e, is64);
            atomicAdd(&lcD[d >> 8], 1);
            atomicAdd(&lcS[s >> 8], 1);
        }
    }
    __syncthreads();
    cntD[b * 256 + t] = lcD[t];
    cntS[b * 256 + t] = lcS[t];

    if (b == 0) {
        if (t == 0) flags[2] = is64;
        if (t == 1) {
            int good = 0;
            for (int i = 0; i < 128; ++i) good += good_halves(hw[i]);
            flags[0] = (good >= 226) ? 1 : 0;
        }
        if (t == 2) {
            int good = 0;
            for (int i = 0; i < 128; ++i) good += good_halves(ww[i]);
            flags[1] = (good >= 226) ? 1 : 0;
        }
    }
}

// ---------------- pass 2: per-bucket exclusive scan over blocks (in-place) --------

__global__ __launch_bounds__(256) void scan_buckets(int* __restrict__ cntD,
                                                    int* __restrict__ cntS,
                                                    int* __restrict__ btotD,
                                                    int* __restrict__ btotS) {
    __shared__ int sm[256];
    int k = blockIdx.x, t = threadIdx.x;
    int b0 = 2 * t, b1 = 2 * t + 1;
    int v0 = (b0 < NB_E) ? cntD[b0 * 256 + k] : 0;
    int v1 = (b1 < NB_E) ? cntD[b1 * 256 + k] : 0;
    int pair = v0 + v1;
    sm[t] = pair;
    __syncthreads();
    for (int off = 1; off < 256; off <<= 1) {
        int u = (t >= off) ? sm[t - off] : 0;
        __syncthreads();
        sm[t] += u;
        __syncthreads();
    }
    int excl = sm[t] - pair;
    if (b0 < NB_E) cntD[b0 * 256 + k] = excl;
    if (b1 < NB_E) cntD[b1 * 256 + k] = excl + v0;
    if (t == 255) btotD[k] = sm[255];
    __syncthreads();
    v0 = (b0 < NB_E) ? cntS[b0 * 256 + k] : 0;
    v1 = (b1 < NB_E) ? cntS[b1 * 256 + k] : 0;
    pair = v0 + v1;
    sm[t] = pair;
    __syncthreads();
    for (int off = 1; off < 256; off <<= 1) {
        int u = (t >= off) ? sm[t - off] : 0;
        __syncthreads();
        sm[t] += u;
        __syncthreads();
    }
    excl = sm[t] - pair;
    if (b0 < NB_E) cntS[b0 * 256 + k] = excl;
    if (b1 < NB_E) cntS[b1 * 256 + k] = excl + v0;
    if (t == 255) btotS[k] = sm[255];
}

// ---------------- pass 3: scatter into buckets (bases re-scanned in LDS) ----------

__global__ __launch_bounds__(256) void part_scatter(const int* __restrict__ src,
                                                    const int* __restrict__ dst,
                                                    const int* __restrict__ offD,
                                                    const int* __restrict__ offS,
                                                    const int* __restrict__ btotD,
                                                    const int* __restrict__ btotS,
                                                    unsigned* __restrict__ epack,
                                                    unsigned char* __restrict__ sloc,
                                                    const int* __restrict__ flags) {
    __shared__ int sm[256];
    __shared__ int runD[256], runS[256];
    int b = blockIdx.x, t = threadIdx.x;
    int v = btotD[t];
    sm[t] = v;
    __syncthreads();
    for (int off = 1; off < 256; off <<= 1) {
        int u = (t >= off) ? sm[t - off] : 0;
        __syncthreads();
        sm[t] += u;
        __syncthreads();
    }
    int baseD = sm[t] - v;
    __syncthreads();
    v = btotS[t];
    sm[t] = v;
    __syncthreads();
    for (int off = 1; off < 256; off <<= 1) {
        int u = (t >= off) ? sm[t - off] : 0;
        __syncthreads();
        sm[t] += u;
        __syncthreads();
    }
    int baseS = sm[t] - v;
    runD[t] = baseD + offD[b * 256 + t];
    runS[t] = baseS + offS[b * 256 + t];
    __syncthreads();
    int is64 = flags[2];
    int base = b * EPB;
#pragma unroll
    for (int i = 0; i < EPB / 256; ++i) {
        int e = base + i * 256 + t;
        if (e < N_EDGES) {
            int d = load_idx(dst, e, is64);
            int s = load_idx(src, e, is64);
            int pd = atomicAdd(&runD[d >> 8], 1);
            epack[pd] = ((unsigned)(d & 255) << 16) | (unsigned)s;
            int ps = atomicAdd(&runS[s >> 8], 1);
            sloc[ps] = (unsigned char)(s & 255);
        }
    }
}

// ---------------- pass 4: per-bucket CSR build + norms + esrc (bases in LDS) -------

__global__ __launch_bounds__(256) void bucket_build(const unsigned* __restrict__ epack,
                                                    const int* __restrict__ btotD,
                                                    const unsigned char* __restrict__ sloc,
                                                    const int* __restrict__ btotS,
                                                    int* __restrict__ rowptr,
                                                    float* __restrict__ normD,
                                                    float* __restrict__ normS,
                                                    unsigned short* __restrict__ esrc) {
    __shared__ int bD[256], bS[256], cnt[256], run[256];
    int k = blockIdx.x, t = threadIdx.x;
    int vD = btotD[t], vS = btotS[t];
    bD[t] = vD; bS[t] = vS;
    __syncthreads();
    for (int off = 1; off < 256; off <<= 1) {
        int uD = (t >= off) ? bD[t - off] : 0;
        int uS = (t >= off) ? bS[t - off] : 0;
        __syncthreads();
        bD[t] += uD; bS[t] += uS;
        __syncthreads();
    }
    int ebeg = (k == 0) ? 0 : bD[k - 1];
    int eend = bD[k];
    int sbeg = (k == 0) ? 0 : bS[k - 1];
    int send = bS[k];

    cnt[t] = 0;
    __syncthreads();
    for (int e = ebeg + t; e < eend; e += 256)
        atomicAdd(&cnt[epack[e] >> 16], 1);
    __syncthreads();
    int v = cnt[t];
    bD[t] = v;  // reuse bD as scan buffer
    __syncthreads();
    for (int off = 1; off < 256; off <<= 1) {
        int u = (t >= off) ? bD[t - off] : 0;
        __syncthreads();
        bD[t] += u;
        __syncthreads();
    }
    int excl = bD[t] - v;
    int n = k * 256 + t;
    if (n < N_NODES) {
        rowptr[n] = ebeg + excl;
        normD[n] = rsqrtf((float)max(v, 1));
    }
    run[t] = excl;
    __syncthreads();
    for (int e = ebeg + t; e < eend; e += 256) {
        unsigned p = epack[e];
        int dl = p >> 16;
        int slot = atomicAdd(&run[dl], 1);
        esrc[ebeg + slot] = (unsigned short)(p & 0xFFFFu);
    }
    if (k == NBKT - 1 && t == 0) rowptr[N_NODES] = N_EDGES;
    // src histogram -> normS
    __syncthreads();
    cnt[t] = 0;
    __syncthreads();
    for (int e = sbeg + t; e < send; e += 256)
        atomicAdd(&cnt[sloc[e]], 1);
    __syncthreads();
    if (n < N_NODES) normS[n] = rsqrtf((float)max(cnt[t], 1));
}

// ---------------- merged prep (W^T bf16 + bias) + cvt (A0 = bf16(h*normS)) --------

__global__ __launch_bounds__(256) void prepcvt_k(const void* __restrict__ W0,
                                                 const void* __restrict__ W1,
                                                 const void* __restrict__ W2,
                                                 const void* __restrict__ b0,
                                                 const void* __restrict__ b1,
                                                 const void* __restrict__ b2,
                                                 unsigned short* __restrict__ WT,
                                                 float* __restrict__ biasc,
                                                 const void* __restrict__ h,
                                                 const float* __restrict__ normS,
                                                 unsigned short* __restrict__ A0,
                                                 const int* __restrict__ flags) {
    int idx = blockIdx.x * 256 + threadIdx.x;
    if (idx < PREP_ITEMS) {
        int wbf = flags[1];
        if (idx < 3 * DIM * DIM) {
            int l = idx / (DIM * DIM);
            int i = idx - l * DIM * DIM;
            int k = i / DIM, n = i - k * DIM;
            const void* Wp = (l == 0) ? W0 : (l == 1) ? W1 : W2;
            WT[l * DIM * DIM + n * DIM + k] = f2bf(rdval(Wp, i, wbf));
        } else {
            int j = idx - 3 * DIM * DIM;
            int l = j / DIM, c = j - l * DIM;
            const void* bp = (l == 0) ? b0 : (l == 1) ? b1 : b2;
            biasc[j] = rdval(bp, c, wbf);
        }
        return;
    }
    int i4 = idx - PREP_ITEMS;
    if (i4 >= N_NODES * DIM / 4) return;
    int hbf = flags[0];
    int i = i4 * 4;
    float ns = normS[i / DIM];
    float v0, v1, v2, v3;
    if (hbf) {
        const __hip_bfloat16* hp = (const __hip_bfloat16*)h + i;
        v0 = __bfloat162float(hp[0]); v1 = __bfloat162float(hp[1]);
        v2 = __bfloat162float(hp[2]); v3 = __bfloat162float(hp[3]);
    } else {
        float4 v = ((const float4*)h)[i4];
        v0 = v.x; v1 = v.y; v2 = v.z; v3 = v.w;
    }
    ushort4 o;
    o.x = f2bf(v0 * ns); o.y = f2bf(v1 * ns);
    o.z = f2bf(v2 * ns); o.w = f2bf(v3 * ns);
    ((ushort4*)A0)[i4] = o;
}

// ---------------- gather: Bm[n] = bf16(normD[n] * sum Abf[esrc[e]]) ----------------
// 12 threads/row, 8 bf16 features (16B uint4) each; fp32 accumulation; unroll x4
// for more outstanding L2/LLC loads. Standalone, no LDS -> full occupancy (R6 lesson).

__device__ __forceinline__ void acc8(float* a, uint4 q) {
    a[0] += __uint_as_float(q.x << 16);
    a[1] += __uint_as_float(q.x & 0xFFFF0000u);
    a[2] += __uint_as_float(q.y << 16);
    a[3] += __uint_as_float(q.y & 0xFFFF0000u);
    a[4] += __uint_as_float(q.z << 16);
    a[5] += __uint_as_float(q.z & 0xFFFF0000u);
    a[6] += __uint_as_float(q.w << 16);
    a[7] += __uint_as_float(q.w & 0xFFFF0000u);
}

__global__ __launch_bounds__(256) void gather_k(const unsigned* __restrict__ Abf,
                                                const float* __restrict__ normD,
                                                const int* __restrict__ rowptr,
                                                const unsigned short* __restrict__ esrc,
                                                unsigned short* __restrict__ Bm) {
    int g = blockIdx.x * 256 + threadIdx.x;
    if (g >= N_NODES * CHB) return;
    int n = g / CHB;
    int c = g - n * CHB;
    int beg = rowptr[n], end = rowptr[n + 1];
    float a[8] = {0.f, 0.f, 0.f, 0.f, 0.f, 0.f, 0.f, 0.f};
    const uint4* Ap = (const uint4*)Abf;
    int k = beg;
    for (; k + 4 <= end; k += 4) {
        int s0 = esrc[k], s1 = esrc[k + 1], s2 = esrc[k + 2], s3 = esrc[k + 3];
        uint4 q0 = Ap[s0 * CHB + c];
        uint4 q1 = Ap[s1 * CHB + c];
        uint4 q2 = Ap[s2 * CHB + c];
        uint4 q3 = Ap[s3 * CHB + c];
        acc8(a, q0); acc8(a, q1); acc8(a, q2); acc8(a, q3);
    }
    for (; k < end; ++k) {
        uint4 q = Ap[esrc[k] * CHB + c];
        acc8(a, q);
    }
    float nd = normD[n];
    uint4 o;
    o.x = (unsigned)f2bf(a[0] * nd) | ((unsigned)f2bf(a[1] * nd) << 16);
    o.y = (unsigned)f2bf(a[2] * nd) | ((unsigned)f2bf(a[3] * nd) << 16);
    o.z = (unsigned)f2bf(a[4] * nd) | ((unsigned)f2bf(a[5] * nd) << 16);
    o.w = (unsigned)f2bf(a[6] * nd) | ((unsigned)f2bf(a[7] * nd) << 16);
    ((uint4*)Bm)[g] = o;
}

// ---------------- MFMA GEMM: t = relu(Bm @ W + b) ----------------
// No LDS, no barriers. 4 waves/block, 16 output rows each. A[m=lane&15][k=quad*8+j]
// from Bm; B from W^T; C/D col=lane&15, row=quad*4+reg (m89/m91).

__global__ __launch_bounds__(256) void gemm_k(const unsigned short* __restrict__ Bm,
                                              const float* __restrict__ normS,
                                              const unsigned short* __restrict__ WTl,
                                              const float* __restrict__ bl,
                                              unsigned short* __restrict__ outA,
                                              void* __restrict__ outLast,
                                              const int* __restrict__ flags, int last) {
    int wv = threadIdx.x >> 6;
    int lane = threadIdx.x & 63;
    int quad = lane >> 4;
    int ln = lane & 15;
    int rowbase = blockIdx.x * 64 + wv * 16;

    const short8* Ap = (const short8*)(Bm + (size_t)(rowbase + ln) * DIM + quad * 8);
    short8 a0 = Ap[0], a1 = Ap[4], a2 = Ap[8];

    float ns[4];
    if (!last) {
#pragma unroll
        for (int r = 0; r < 4; ++r)
            ns[r] = normS[min(rowbase + quad * 4 + r, N_NODES - 1)];
    }
    int obf = flags[0];

#pragma unroll
    for (int ct = 0; ct < 6; ++ct) {
        const short8* Wp = (const short8*)(WTl + (size_t)(ct * 16 + ln) * DIM + quad * 8);
        short8 b0 = Wp[0], b1 = Wp[4], b2 = Wp[8];
        f32x4 acc = {0.f, 0.f, 0.f, 0.f};
        acc = __builtin_amdgcn_mfma_f32_16x16x32_bf16(a0, b0, acc, 0, 0, 0);
        acc = __builtin_amdgcn_mfma_f32_16x16x32_bf16(a1, b1, acc, 0, 0, 0);
        acc = __builtin_amdgcn_mfma_f32_16x16x32_bf16(a2, b2, acc, 0, 0, 0);
        int col = ct * 16 + ln;
        float bv = bl[col];
#pragma unroll
        for (int r = 0; r < 4; ++r) {
            int row = rowbase + quad * 4 + r;
            if (row < N_NODES) {
                float v = fmaxf(acc[r] + bv, 0.f);
                size_t idx = (size_t)row * DIM + col;
                if (last) {
                    if (obf)
                        ((__hip_bfloat16*)outLast)[idx] = __float2bfloat16(v);
                    else
                        ((float*)outLast)[idx] = v;
                } else {
                    outA[idx] = f2bf(v * ns[r]);
                }
            }
        }
    }
}

// ---------------- host launch ----------------

extern "C" void kernel_launch(void* const* d_in, const int* in_sizes, int n_in,
                              void* d_out, int out_size, void* d_ws, size_t ws_size,
                              hipStream_t stream) {
    const void* h = d_in[0];
    const int* src = (const int*)d_in[1];
    const int* dst = (const int*)d_in[2];

    // workspace layout (4B units; all sections 16B-aligned)
    int* flags = (int*)d_ws;                            // 4
    int* cntD = flags + 4;                              // 100096
    int* cntS = cntD + NB_E * 256;                      // 100096
    int* btotD = cntS + NB_E * 256;                     // 256
    int* btotS = btotD + 256;                           // 256
    int* rowptr = btotS + 256;                          // 50004
    float* normS = (float*)(rowptr + 50004);            // 50000
    float* normD = normS + N_NODES;                     // 50000
    unsigned short* WT = (unsigned short*)(normD + N_NODES);  // 3*9216 us
    float* biasc = (float*)(WT + 3 * DIM * DIM);        // 288
    unsigned* epack = (unsigned*)(biasc + 3 * DIM);     // 800000
    unsigned char* sloc = (unsigned char*)(epack + N_EDGES);   // 800000 B
    unsigned short* esrc = (unsigned short*)(sloc + N_EDGES);  // 800000 us
    unsigned short* Bm = esrc + N_EDGES;                // N_PAD*96 us
    unsigned short* A0 = Bm + (size_t)N_PAD * DIM;      // 4.8M us
    unsigned short* A1 = A0 + (size_t)N_NODES * DIM;    // 4.8M us

    part_count<<<NB_E, 256, 0, stream>>>(src, dst, (const unsigned*)h,
                                         (const unsigned*)d_in[3], cntD, cntS, flags);
    scan_buckets<<<256, 256, 0, stream>>>(cntD, cntS, btotD, btotS);
    part_scatter<<<NB_E, 256, 0, stream>>>(src, dst, cntD, cntS, btotD, btotS,
                                           epack, sloc, flags);
    bucket_build<<<NBKT, 256, 0, stream>>>(epack, btotD, sloc, btotS,
                                           rowptr, normD, normS, esrc);
    prepcvt_k<<<(PREP_ITEMS + N_NODES * DIM / 4 + 255) / 256, 256, 0, stream>>>(
        d_in[3], d_in[5], d_in[7], d_in[4], d_in[6], d_in[8], WT, biasc,
        h, normS, A0, flags);

    const int ggrid = (N_NODES * CHB + 255) / 256;
    gather_k<<<ggrid, 256, 0, stream>>>((const unsigned*)A0, normD, rowptr, esrc, Bm);
    gemm_k<<<NTILES, 256, 0, stream>>>(Bm, normS, WT, biasc, A1, nullptr, flags, 0);
    gather_k<<<ggrid, 256, 0, stream>>>((const unsigned*)A1, normD, rowptr, esrc, Bm);
    gemm_k<<<NTILES, 256, 0, stream>>>(Bm, normS, WT + DIM * DIM, biasc + DIM,
                                       A0, nullptr, flags, 0);
    gather_k<<<ggrid, 256, 0, stream>>>((const unsigned*)A0, normD, rowptr, esrc, Bm);
    gemm_k<<<NTILES, 256, 0, stream>>>(Bm, normS, WT + 2 * DIM * DIM, biasc + 2 * DIM,
                                       nullptr, d_out, flags, 1);
}